// Round 2
// baseline (331.009 us; speedup 1.0000x reference)
//
#include <hip/hip_runtime.h>

#define B_ 4
#define H_ 64
#define W_ 64
#define C_ 32
#define N_ 4096
#define E_ 131072

typedef _Float16 half8 __attribute__((ext_vector_type(8)));
typedef float f32x4 __attribute__((ext_vector_type(4)));

__device__ __forceinline__ float gelu_f(float x) {
    return 0.5f * x * (1.0f + erff(x * 0.70710678118654752f));
}

#define TWOPI_64 (6.2831853071795864769f / 64.0f)

__device__ __forceinline__ void block_reduce2(float& s, float& s2, float* red) {
    #pragma unroll
    for (int off = 32; off > 0; off >>= 1) {
        s  += __shfl_down(s, off, 64);
        s2 += __shfl_down(s2, off, 64);
    }
    int lane = threadIdx.x & 63, wv = threadIdx.x >> 6;
    __syncthreads();
    if (lane == 0) { red[wv] = s; red[wv + 4] = s2; }
    __syncthreads();
    s  = red[0] + red[1] + red[2] + red[3];
    s2 = red[4] + red[5] + red[6] + red[7];
}

// ---------------- InstanceNorm of input: per (b,h) over (w,c) = 2048 vals ----------------
__global__ __launch_bounds__(256) void k_inorm(const float* __restrict__ nodes,
                                               float* __restrict__ xn) {
    int bh = blockIdx.x;
    int t = threadIdx.x;
    const float4* src = (const float4*)(nodes + bh * 2048);
    float4* dst = (float4*)(xn + bh * 2048);
    float4 v0 = src[t * 2], v1 = src[t * 2 + 1];
    float s  = v0.x + v0.y + v0.z + v0.w + v1.x + v1.y + v1.z + v1.w;
    float s2 = v0.x*v0.x + v0.y*v0.y + v0.z*v0.z + v0.w*v0.w
             + v1.x*v1.x + v1.y*v1.y + v1.z*v1.z + v1.w*v1.w;
    __shared__ float red[8];
    block_reduce2(s, s2, red);
    float mean = s * (1.0f / 2048.0f);
    float var  = s2 * (1.0f / 2048.0f) - mean * mean;
    float sc = rsqrtf(var + 1e-5f);
    v0.x = (v0.x - mean) * sc; v0.y = (v0.y - mean) * sc;
    v0.z = (v0.z - mean) * sc; v0.w = (v0.w - mean) * sc;
    v1.x = (v1.x - mean) * sc; v1.y = (v1.y - mean) * sc;
    v1.z = (v1.z - mean) * sc; v1.w = (v1.w - mean) * sc;
    dst[t * 2] = v0; dst[t * 2 + 1] = v1;
}

// ---------------- ker_w2 [64][1024] f32 -> MFMA-fragment-ordered hi/lo f16 ----------------
// frag id = (i*2 + t2)*2 + kh;  element: k = kh*32 + quad*8 + j, n = i*32 + t2*16 + l15
// linear: g = fid*512 + lane*8 + j
__global__ __launch_bounds__(256) void k_w2t(const float* __restrict__ w2,
                                             _Float16* __restrict__ whi,
                                             _Float16* __restrict__ wlo) {
    int g = blockIdx.x * 256 + threadIdx.x;  // over 65536
    int j = g & 7, l = (g >> 3) & 63, fid = g >> 9;
    int i = fid >> 2, t2 = (fid >> 1) & 1, kh = fid & 1;
    int quad = l >> 4, l15 = l & 15;
    int k = kh * 32 + quad * 8 + j;
    int n = i * 32 + t2 * 16 + l15;
    float v = w2[k * 1024 + n];
    _Float16 hi = (_Float16)v;
    whi[g] = hi;
    wlo[g] = (_Float16)(v - (float)hi);
}

// ---------------- xb2[b,n,o] = sum_i xn[b,n,i]*ker_b2[i*32+o] ----------------
__global__ __launch_bounds__(256) void k_xb2(const float* __restrict__ xn,
                                             const float* __restrict__ b2,
                                             float* __restrict__ xb2) {
    int g = blockIdx.x * 256 + threadIdx.x;  // over 524288
    int o = g & 31;
    int nn = (g >> 5) & 4095;
    int b = g >> 17;
    const float* xp = xn + (b * 4096 + nn) * 32;
    float acc = 0.f;
    #pragma unroll
    for (int i = 0; i < 32; ++i) acc += xp[i] * b2[i * 32 + o];
    xb2[g] = acc;
}

// ---------------- forward DFT stage 1 (over w): G[b,h,ky,i], ky=0..15 ----------------
__global__ __launch_bounds__(256) void k_fft_g(const float* __restrict__ xn,
                                               float* __restrict__ Gre, float* __restrict__ Gim) {
    int bh = blockIdx.x;
    int t = threadIdx.x;
    __shared__ float sx[2048];
    __shared__ float tc[64], ts[64];
    const float4* src = (const float4*)(xn + bh * 2048);
    ((float4*)sx)[t * 2] = src[t * 2];
    ((float4*)sx)[t * 2 + 1] = src[t * 2 + 1];
    if (t < 64) { float a = TWOPI_64 * t; tc[t] = cosf(a); ts[t] = sinf(a); }
    __syncthreads();
    #pragma unroll
    for (int rep = 0; rep < 2; ++rep) {
        int oi = rep * 256 + t;
        int ky = oi >> 5, i = oi & 31;
        float re = 0.f, im = 0.f;
        for (int w = 0; w < 64; ++w) {
            float v = sx[w * 32 + i];
            int m = (ky * w) & 63;
            re += v * tc[m];
            im -= v * ts[m];
        }
        Gre[bh * 512 + oi] = re;
        Gim[bh * 512 + oi] = im;
    }
}

// ---------------- forward DFT stage 2 (over h): Xf[b,kxi,ky,i] ----------------
__global__ __launch_bounds__(256) void k_fft_xf(const float* __restrict__ Gre, const float* __restrict__ Gim,
                                                float* __restrict__ Xr, float* __restrict__ Xi) {
    int bid = blockIdx.x;  // 0..127 = (b, kxi)
    int b = bid >> 5, kxi = bid & 31;
    int kx = kxi + (kxi < 16 ? 0 : 32);
    int t = threadIdx.x;
    __shared__ float tc[64], ts[64];
    if (t < 64) { float a = TWOPI_64 * t; tc[t] = cosf(a); ts[t] = sinf(a); }
    __syncthreads();
    #pragma unroll
    for (int rep = 0; rep < 2; ++rep) {
        int oi = rep * 256 + t;
        int ky = oi >> 5, i = oi & 31;
        float re = 0.f, im = 0.f;
        for (int h = 0; h < 64; ++h) {
            int gidx = (b * 64 + h) * 512 + ky * 32 + i;
            float gr = Gre[gidx], gi = Gim[gidx];
            int m = (kx * h) & 63;
            float c = tc[m], sv = ts[m];
            re += gr * c + gi * sv;   // * e^{-i theta}
            im += gi * c - gr * sv;
        }
        Xr[bid * 512 + oi] = re;
        Xi[bid * 512 + oi] = im;
    }
}

// ---------------- spectral multiply ----------------
__global__ __launch_bounds__(256) void k_fft_yf(const float* __restrict__ Xr, const float* __restrict__ Xi,
                                                const float* __restrict__ w1re, const float* __restrict__ w1im,
                                                const float* __restrict__ w2re, const float* __restrict__ w2im,
                                                float* __restrict__ Yr, float* __restrict__ Yi) {
    int bid = blockIdx.x;  // (b, kxi)
    int kxi = bid & 31;
    int x = kxi & 15;
    const float* wre = (kxi < 16) ? w1re : w2re;
    const float* wim = (kxi < 16) ? w1im : w2im;
    int t = threadIdx.x;
    __shared__ float sXr[16 * 33], sXi[16 * 33];
    for (int f = t; f < 512; f += 256) {
        sXr[(f >> 5) * 33 + (f & 31)] = Xr[bid * 512 + f];
        sXi[(f >> 5) * 33 + (f & 31)] = Xi[bid * 512 + f];
    }
    __syncthreads();
    #pragma unroll
    for (int rep = 0; rep < 2; ++rep) {
        int oi = rep * 256 + t;
        int ky = oi & 15, o = oi >> 4;
        float re = 0.f, im = 0.f;
        for (int i = 0; i < 32; ++i) {
            float xr = sXr[ky * 33 + i], xi = sXi[ky * 33 + i];
            int widx = (i * 32 + o) * 256 + x * 16 + ky;
            float wr = wre[widx], wi = wim[widx];
            re += xr * wr - xi * wi;
            im += xr * wi + xi * wr;
        }
        Yr[bid * 512 + ky * 32 + o] = re;
        Yi[bid * 512 + ky * 32 + o] = im;
    }
}

// ---------------- inverse stage 1 (ifft over h): Z[b,h,ky,o] ----------------
__global__ __launch_bounds__(256) void k_fft_z(const float* __restrict__ Yr, const float* __restrict__ Yi,
                                               float* __restrict__ Zr, float* __restrict__ Zi) {
    int bh = blockIdx.x;
    int b = bh >> 6, h = bh & 63;
    int t = threadIdx.x;
    __shared__ float tc[64], ts[64];
    if (t < 64) { float a = TWOPI_64 * t; tc[t] = cosf(a); ts[t] = sinf(a); }
    __syncthreads();
    #pragma unroll
    for (int rep = 0; rep < 2; ++rep) {
        int oi = rep * 256 + t;
        int ky = oi >> 5, o = oi & 31;
        float re = 0.f, im = 0.f;
        for (int kxi = 0; kxi < 32; ++kxi) {
            int kx = kxi + (kxi < 16 ? 0 : 32);
            int m = (kx * h) & 63;
            float c = tc[m], sv = ts[m];
            int yidx = (b * 32 + kxi) * 512 + ky * 32 + o;
            float yr = Yr[yidx], yi = Yi[yidx];
            re += yr * c - yi * sv;   // * e^{+i theta}
            im += yr * sv + yi * c;
        }
        Zr[bh * 512 + oi] = re;
        Zi[bh * 512 + oi] = im;
    }
}

// ---------------- irfft stage 2 (over w) + InstanceNorm + MLP -> osum = x1 ----------------
__global__ __launch_bounds__(256) void k_x1(const float* __restrict__ Zr, const float* __restrict__ Zi,
                                            const float* __restrict__ w1, const float* __restrict__ b1,
                                            const float* __restrict__ w2, const float* __restrict__ b2,
                                            float* __restrict__ osum) {
    int bh = blockIdx.x;
    int t = threadIdx.x;
    __shared__ float sZr[16 * 33], sZi[16 * 33];
    __shared__ float sP[64 * 33];
    __shared__ float sH[64 * 65];
    __shared__ float sW1[2048], sW2[2048];
    __shared__ float tc[64], ts[64];
    __shared__ float red[8];
    if (t < 64) { float a = TWOPI_64 * t; tc[t] = cosf(a); ts[t] = sinf(a); }
    for (int f = t; f < 512; f += 256) {
        sZr[(f >> 5) * 33 + (f & 31)] = Zr[bh * 512 + f];
        sZi[(f >> 5) * 33 + (f & 31)] = Zi[bh * 512 + f];
    }
    for (int f = t; f < 2048; f += 256) { sW1[f] = w1[f]; sW2[f] = w2[f]; }
    __syncthreads();
    float s = 0.f, s2 = 0.f;
    float vals[8];
    #pragma unroll
    for (int rep = 0; rep < 8; ++rep) {
        int idx = rep * 256 + t;
        int w = idx >> 5, o = idx & 31;
        float acc = sZr[o];  // ky=0: real part only (irfft drops imag of DC bin)
        #pragma unroll
        for (int ky = 1; ky < 16; ++ky) {
            int m = (ky * w) & 63;
            acc += 2.0f * (sZr[ky * 33 + o] * tc[m] - sZi[ky * 33 + o] * ts[m]);
        }
        acc *= (1.0f / 4096.0f);
        vals[rep] = acc;
        s += acc; s2 += acc * acc;
    }
    block_reduce2(s, s2, red);
    float mean = s * (1.0f / 2048.0f);
    float sc = rsqrtf(s2 * (1.0f / 2048.0f) - mean * mean + 1e-5f);
    #pragma unroll
    for (int rep = 0; rep < 8; ++rep) {
        int idx = rep * 256 + t;
        sP[(idx >> 5) * 33 + (idx & 31)] = (vals[rep] - mean) * sc;
    }
    __syncthreads();
    #pragma unroll
    for (int rep = 0; rep < 16; ++rep) {
        int idx = rep * 256 + t;
        int w = idx >> 6, k = idx & 63;
        float acc = b1[k];
        #pragma unroll
        for (int c = 0; c < 32; ++c) acc += sP[w * 33 + c] * sW1[c * 64 + k];
        sH[w * 65 + k] = gelu_f(acc);
    }
    __syncthreads();
    #pragma unroll
    for (int rep = 0; rep < 8; ++rep) {
        int idx = rep * 256 + t;
        int w = idx >> 5, o = idx & 31;
        float acc = b2[o];
        #pragma unroll
        for (int k = 0; k < 64; ++k) acc += sH[w * 65 + k] * sW2[k * 32 + o];
        osum[bh * 2048 + idx] = acc;
    }
}

// ---------------- x2 = InstanceNorm(MLP(xn)); osum += x2 ----------------
__global__ __launch_bounds__(256) void k_x2(const float* __restrict__ xn,
                                            const float* __restrict__ w1, const float* __restrict__ b1,
                                            const float* __restrict__ w2, const float* __restrict__ b2,
                                            float* __restrict__ osum) {
    int bh = blockIdx.x;
    int t = threadIdx.x;
    __shared__ float sX[64 * 33];
    __shared__ float sH[64 * 65];
    __shared__ float sW1[2048], sW2[2048];
    __shared__ float red[8];
    for (int f = t; f < 2048; f += 256) {
        sX[(f >> 5) * 33 + (f & 31)] = xn[bh * 2048 + f];
        sW1[f] = w1[f]; sW2[f] = w2[f];
    }
    __syncthreads();
    #pragma unroll
    for (int rep = 0; rep < 16; ++rep) {
        int idx = rep * 256 + t;
        int w = idx >> 6, k = idx & 63;
        float acc = b1[k];
        #pragma unroll
        for (int c = 0; c < 32; ++c) acc += sX[w * 33 + c] * sW1[c * 64 + k];
        sH[w * 65 + k] = gelu_f(acc);
    }
    __syncthreads();
    float s = 0.f, s2 = 0.f;
    float vals[8];
    #pragma unroll
    for (int rep = 0; rep < 8; ++rep) {
        int idx = rep * 256 + t;
        int w = idx >> 5, o = idx & 31;
        float acc = b2[o];
        #pragma unroll
        for (int k = 0; k < 64; ++k) acc += sH[w * 65 + k] * sW2[k * 32 + o];
        vals[rep] = acc;
        s += acc; s2 += acc * acc;
    }
    block_reduce2(s, s2, red);
    float mean = s * (1.0f / 2048.0f);
    float sc = rsqrtf(s2 * (1.0f / 2048.0f) - mean * mean + 1e-5f);
    #pragma unroll
    for (int rep = 0; rep < 8; ++rep) {
        int idx = rep * 256 + t;
        osum[bh * 2048 + idx] += (vals[rep] - mean) * sc;
    }
}

// ---------------- GNO: 128 edges/block; wave = 64 edges x 16-o half; hi/lo f16 MFMA ----------------
// wmat[e][n] = sum_k h[e][k]*w2[k][n], n = i*32+o;  msg[b][e][o] += x[b,src_e,i]*wmat[e][i*32+o]
__global__ __launch_bounds__(256, 2) void k_gno(const float* __restrict__ ea,
                                                const float* __restrict__ kw1, const float* __restrict__ kb1,
                                                const _Float16* __restrict__ whi, const _Float16* __restrict__ wlo,
                                                const float* __restrict__ xn, const float* __restrict__ xb2,
                                                const int* __restrict__ ei,
                                                float* __restrict__ agg) {
    // phase A: sbuf = h[128][68] f32 (8704 floats); phase B: sbuf = sxT[4][32][132] (16896 floats)
    __shared__ __align__(16) float sbuf[16896];
    __shared__ int ssrc[128], sdst[128];
    int t = threadIdx.x;
    int lane = t & 63, wv = t >> 6, quad = lane >> 4, l15 = lane & 15;
    int eg = wv >> 1;      // edge group: edges [eg*64, eg*64+64)
    int t2 = wv & 1;       // o-half: o = t2*16 + l15
    int e0 = blockIdx.x * 128;

    // ---- phase 1: edge indices + h = gelu(edge_attr @ kw1 + kb1) (f32, stride 68) ----
    if (t < 128) ssrc[t] = ei[e0 + t];
    else         sdst[t - 128] = ei[E_ + e0 + t - 128];
    {
        int r = t >> 1, k0 = (t & 1) * 32;
        const float* ep = ea + (e0 + r) * 6;
        float e6[6];
        #pragma unroll
        for (int d = 0; d < 6; ++d) e6[d] = ep[d];
        #pragma unroll
        for (int kk = 0; kk < 32; ++kk) {
            int k = k0 + kk;
            float acc = kb1[k];
            #pragma unroll
            for (int d = 0; d < 6; ++d) acc += e6[d] * kw1[d * 64 + k];
            sbuf[r * 68 + k] = gelu_f(acc);
        }
    }
    __syncthreads();

    // ---- phase 2: build A fragments (hi/lo) from sbuf ----
    half8 ahi[4][2], alo[4][2];
    #pragma unroll
    for (int et = 0; et < 4; ++et) {
        #pragma unroll
        for (int kh = 0; kh < 2; ++kh) {
            const float* hp = sbuf + (eg * 64 + et * 16 + l15) * 68 + kh * 32 + quad * 8;
            float4 h0 = *(const float4*)hp;
            float4 h1 = *(const float4*)(hp + 4);
            float hv[8] = {h0.x, h0.y, h0.z, h0.w, h1.x, h1.y, h1.z, h1.w};
            half8 hh, hl;
            #pragma unroll
            for (int j = 0; j < 8; ++j) {
                _Float16 hi = (_Float16)hv[j];
                hh[j] = hi;
                hl[j] = (_Float16)(hv[j] - (float)hi);
            }
            ahi[et][kh] = hh;
            alo[et][kh] = hl;
        }
    }
    __syncthreads();

    // ---- phase 3: gather x rows transposed into sxT[b][i][e] (reuses sbuf) ----
    #pragma unroll
    for (int rep = 0; rep < 2; ++rep) {
        int b = t & 3, r = (t >> 2) + rep * 64;
        int s = ssrc[r];
        const float4* xp = (const float4*)(xn + (b * 4096 + s) * 32);
        #pragma unroll
        for (int q = 0; q < 8; ++q) {
            float4 v = xp[q];
            float* dp = sbuf + (b * 32 + q * 4) * 132 + r;
            dp[0]       = v.x;
            dp[132]     = v.y;
            dp[264]     = v.z;
            dp[396]     = v.w;
        }
    }
    __syncthreads();

    // ---- main loop over i ----
    float msg[4][4][4];  // [b][et][r], o = t2*16+l15
    #pragma unroll
    for (int b = 0; b < 4; ++b)
        #pragma unroll
        for (int et = 0; et < 4; ++et)
            #pragma unroll
            for (int r = 0; r < 4; ++r) msg[b][et][r] = 0.f;

    for (int i = 0; i < 32; ++i) {
        int f0 = (i * 4 + t2 * 2) * 512 + lane * 8;
        half8 bhi0 = *(const half8*)(whi + f0);
        half8 bhi1 = *(const half8*)(whi + f0 + 512);
        half8 blo0 = *(const half8*)(wlo + f0);
        half8 blo1 = *(const half8*)(wlo + f0 + 512);
        f32x4 acc[4];
        #pragma unroll
        for (int et = 0; et < 4; ++et) {
            f32x4 a = {0.f, 0.f, 0.f, 0.f};
            a = __builtin_amdgcn_mfma_f32_16x16x32_f16(ahi[et][0], bhi0, a, 0, 0, 0);
            a = __builtin_amdgcn_mfma_f32_16x16x32_f16(ahi[et][1], bhi1, a, 0, 0, 0);
            a = __builtin_amdgcn_mfma_f32_16x16x32_f16(ahi[et][0], blo0, a, 0, 0, 0);
            a = __builtin_amdgcn_mfma_f32_16x16x32_f16(ahi[et][1], blo1, a, 0, 0, 0);
            a = __builtin_amdgcn_mfma_f32_16x16x32_f16(alo[et][0], bhi0, a, 0, 0, 0);
            a = __builtin_amdgcn_mfma_f32_16x16x32_f16(alo[et][1], bhi1, a, 0, 0, 0);
            acc[et] = a;
        }
        #pragma unroll
        for (int b = 0; b < 4; ++b) {
            #pragma unroll
            for (int et = 0; et < 4; ++et) {
                const float4 xv = *(const float4*)(sbuf + (b * 32 + i) * 132 + eg * 64 + et * 16 + quad * 4);
                msg[b][et][0] += xv.x * acc[et][0];
                msg[b][et][1] += xv.y * acc[et][1];
                msg[b][et][2] += xv.z * acc[et][2];
                msg[b][et][3] += xv.w * acc[et][3];
            }
        }
    }

    // ---- scatter: agg[b, dst, o] += msg + xb2[b, src, o] ----
    int o = t2 * 16 + l15;
    #pragma unroll
    for (int et = 0; et < 4; ++et) {
        #pragma unroll
        for (int r = 0; r < 4; ++r) {
            int row = eg * 64 + et * 16 + quad * 4 + r;
            int s = ssrc[row], d = sdst[row];
            #pragma unroll
            for (int b = 0; b < 4; ++b) {
                atomicAdd(&agg[(b * 4096 + d) * 32 + o], msg[b][et][r] + xb2[(b * 4096 + s) * 32 + o]);
            }
        }
    }
}

// ---------------- final: out = gelu(osum + agg + xn@root + gbias) ----------------
__global__ __launch_bounds__(256) void k_final(const float* __restrict__ osum, const float* __restrict__ agg,
                                               const float* __restrict__ xn, const float* __restrict__ root,
                                               const float* __restrict__ gbias, float* __restrict__ out) {
    int bh = blockIdx.x;
    int t = threadIdx.x;
    __shared__ float sX[64 * 33];
    __shared__ float sR[1024];
    for (int f = t; f < 2048; f += 256) sX[(f >> 5) * 33 + (f & 31)] = xn[bh * 2048 + f];
    for (int f = t; f < 1024; f += 256) sR[f] = root[f];
    __syncthreads();
    #pragma unroll
    for (int rep = 0; rep < 8; ++rep) {
        int idx = rep * 256 + t;
        int w = idx >> 5, o = idx & 31;
        float acc = gbias[o] + osum[bh * 2048 + idx] + agg[bh * 2048 + idx];
        #pragma unroll
        for (int c = 0; c < 32; ++c) acc += sX[w * 33 + c] * sR[c * 32 + o];
        out[bh * 2048 + idx] = gelu_f(acc);
    }
}

extern "C" void kernel_launch(void* const* d_in, const int* in_sizes, int n_in,
                              void* d_out, int out_size, void* d_ws, size_t ws_size,
                              hipStream_t stream) {
    (void)in_sizes; (void)n_in; (void)out_size; (void)ws_size;
    const float* nodes  = (const float*)d_in[0];
    const int*   eidx   = (const int*)d_in[1];
    const float* eattr  = (const float*)d_in[2];
    const float* w1re   = (const float*)d_in[3];
    const float* w1im   = (const float*)d_in[4];
    const float* w2re   = (const float*)d_in[5];
    const float* w2im   = (const float*)d_in[6];
    const float* mlp_w1 = (const float*)d_in[7];
    const float* mlp_b1 = (const float*)d_in[8];
    const float* mlp_w2 = (const float*)d_in[9];
    const float* mlp_b2 = (const float*)d_in[10];
    const float* wm_w1  = (const float*)d_in[11];
    const float* wm_b1  = (const float*)d_in[12];
    const float* wm_w2  = (const float*)d_in[13];
    const float* wm_b2  = (const float*)d_in[14];
    const float* ker_w1 = (const float*)d_in[15];
    const float* ker_b1 = (const float*)d_in[16];
    const float* ker_w2 = (const float*)d_in[17];
    const float* ker_b2 = (const float*)d_in[18];
    const float* root   = (const float*)d_in[19];
    const float* gbias  = (const float*)d_in[20];
    float* out = (float*)d_out;

    char* ws = (char*)d_ws;
    size_t off = 0;
    auto alloc = [&](size_t bytes) {
        void* p = ws + off;
        off += (bytes + 255) & ~(size_t)255;
        return p;
    };
    float* xn   = (float*)alloc(524288 * 4);
    float* xb2  = (float*)alloc(524288 * 4);
    float* agg  = (float*)alloc(524288 * 4);
    float* osum = (float*)alloc(524288 * 4);
    float* Gre  = (float*)alloc(131072 * 4);
    float* Gim  = (float*)alloc(131072 * 4);
    float* Xr   = (float*)alloc(65536 * 4);
    float* Xi   = (float*)alloc(65536 * 4);
    float* Yr   = (float*)alloc(65536 * 4);
    float* Yi   = (float*)alloc(65536 * 4);
    float* Zr   = (float*)alloc(131072 * 4);
    float* Zi   = (float*)alloc(131072 * 4);
    _Float16* whi = (_Float16*)alloc(65536 * 2);
    _Float16* wlo = (_Float16*)alloc(65536 * 2);

    hipMemsetAsync(agg, 0, 524288 * 4, stream);
    k_inorm<<<256, 256, 0, stream>>>(nodes, xn);
    k_w2t<<<256, 256, 0, stream>>>(ker_w2, whi, wlo);
    k_xb2<<<2048, 256, 0, stream>>>(xn, ker_b2, xb2);
    k_fft_g<<<256, 256, 0, stream>>>(xn, Gre, Gim);
    k_fft_xf<<<128, 256, 0, stream>>>(Gre, Gim, Xr, Xi);
    k_fft_yf<<<128, 256, 0, stream>>>(Xr, Xi, w1re, w1im, w2re, w2im, Yr, Yi);
    k_fft_z<<<256, 256, 0, stream>>>(Yr, Yi, Zr, Zi);
    k_x1<<<256, 256, 0, stream>>>(Zr, Zi, mlp_w1, mlp_b1, mlp_w2, mlp_b2, osum);
    k_x2<<<256, 256, 0, stream>>>(xn, wm_w1, wm_b1, wm_w2, wm_b2, osum);
    k_gno<<<1024, 256, 0, stream>>>(eattr, ker_w1, ker_b1, whi, wlo, xn, xb2, eidx, agg);
    k_final<<<256, 256, 0, stream>>>(osum, agg, xn, root, gbias, out);
}

// Round 3
// 318.422 us; speedup vs baseline: 1.0395x; 1.0395x over previous
//
#include <hip/hip_runtime.h>

#define B_ 4
#define H_ 64
#define W_ 64
#define C_ 32
#define N_ 4096
#define E_ 131072

typedef _Float16 half8 __attribute__((ext_vector_type(8)));
typedef float f32x4 __attribute__((ext_vector_type(4)));

__device__ __forceinline__ float gelu_f(float x) {
    return 0.5f * x * (1.0f + erff(x * 0.70710678118654752f));
}

#define TWOPI_64 (6.2831853071795864769f / 64.0f)

__device__ __forceinline__ void block_reduce2(float& s, float& s2, float* red) {
    #pragma unroll
    for (int off = 32; off > 0; off >>= 1) {
        s  += __shfl_down(s, off, 64);
        s2 += __shfl_down(s2, off, 64);
    }
    int lane = threadIdx.x & 63, wv = threadIdx.x >> 6;
    __syncthreads();
    if (lane == 0) { red[wv] = s; red[wv + 4] = s2; }
    __syncthreads();
    s  = red[0] + red[1] + red[2] + red[3];
    s2 = red[4] + red[5] + red[6] + red[7];
}

// ---------------- fused: InstanceNorm + DFT stage1 + agg-zero | w2 repack ----------------
// blocks 0..255: per (b,h): xn = IN(nodes); G[b,h,ky,i]; zero agg slice
// blocks 256..383: ker_w2 [64][1024] f32 -> MFMA-fragment-ordered hi/lo f16
__global__ __launch_bounds__(256) void k_pre(const float* __restrict__ nodes,
                                             const float* __restrict__ w2,
                                             float* __restrict__ xn,
                                             float* __restrict__ agg,
                                             float* __restrict__ Gre, float* __restrict__ Gim,
                                             _Float16* __restrict__ whi, _Float16* __restrict__ wlo) {
    int t = threadIdx.x;
    if (blockIdx.x >= 256) {
        int g0 = (blockIdx.x - 256) * 512 + t;
        #pragma unroll
        for (int rep = 0; rep < 2; ++rep) {
            int g = g0 + rep * 256;
            int j = g & 7, l = (g >> 3) & 63, fid = g >> 9;
            int i = fid >> 2, t2 = (fid >> 1) & 1, kh = fid & 1;
            int quad = l >> 4, l15 = l & 15;
            int k = kh * 32 + quad * 8 + j;
            int n = i * 32 + t2 * 16 + l15;
            float v = w2[k * 1024 + n];
            _Float16 hi = (_Float16)v;
            whi[g] = hi;
            wlo[g] = (_Float16)(v - (float)hi);
        }
        return;
    }
    int bh = blockIdx.x;
    __shared__ float sx[2048];
    __shared__ float tc[64], ts[64];
    __shared__ float red[8];
    const float4* src = (const float4*)(nodes + bh * 2048);
    float4* dst = (float4*)(xn + bh * 2048);
    float4* az = (float4*)(agg + bh * 2048);
    if (t < 64) { float a = TWOPI_64 * t; tc[t] = cosf(a); ts[t] = sinf(a); }
    float4 v0 = src[t * 2], v1 = src[t * 2 + 1];
    float s  = v0.x + v0.y + v0.z + v0.w + v1.x + v1.y + v1.z + v1.w;
    float s2 = v0.x*v0.x + v0.y*v0.y + v0.z*v0.z + v0.w*v0.w
             + v1.x*v1.x + v1.y*v1.y + v1.z*v1.z + v1.w*v1.w;
    block_reduce2(s, s2, red);
    float mean = s * (1.0f / 2048.0f);
    float var  = s2 * (1.0f / 2048.0f) - mean * mean;
    float sc = rsqrtf(var + 1e-5f);
    v0.x = (v0.x - mean) * sc; v0.y = (v0.y - mean) * sc;
    v0.z = (v0.z - mean) * sc; v0.w = (v0.w - mean) * sc;
    v1.x = (v1.x - mean) * sc; v1.y = (v1.y - mean) * sc;
    v1.z = (v1.z - mean) * sc; v1.w = (v1.w - mean) * sc;
    dst[t * 2] = v0; dst[t * 2 + 1] = v1;
    float4 z = {0.f, 0.f, 0.f, 0.f};
    az[t * 2] = z; az[t * 2 + 1] = z;
    ((float4*)sx)[t * 2] = v0;
    ((float4*)sx)[t * 2 + 1] = v1;
    __syncthreads();
    #pragma unroll
    for (int rep = 0; rep < 2; ++rep) {
        int oi = rep * 256 + t;
        int ky = oi >> 5, i = oi & 31;
        float re = 0.f, im = 0.f;
        #pragma unroll 8
        for (int w = 0; w < 64; ++w) {
            float v = sx[w * 32 + i];
            int m = (ky * w) & 63;
            re += v * tc[m];
            im -= v * ts[m];
        }
        Gre[bh * 512 + oi] = re;
        Gim[bh * 512 + oi] = im;
    }
}

// ---------------- fused: DFT stage2 (over h) + spectral multiply -> Yf ----------------
__global__ __launch_bounds__(256) void k_fxy(const float* __restrict__ Gre, const float* __restrict__ Gim,
                                             const float* __restrict__ w1re, const float* __restrict__ w1im,
                                             const float* __restrict__ w2re, const float* __restrict__ w2im,
                                             float* __restrict__ Yr, float* __restrict__ Yi) {
    int bid = blockIdx.x;  // 0..127 = (b, kxi)
    int b = bid >> 5, kxi = bid & 31;
    int kx = kxi + (kxi < 16 ? 0 : 32);
    int x = kxi & 15;
    const float* wre = (kxi < 16) ? w1re : w2re;
    const float* wim = (kxi < 16) ? w1im : w2im;
    int t = threadIdx.x;
    __shared__ float tc[64], ts[64];
    __shared__ float sXr[16 * 33], sXi[16 * 33];
    if (t < 64) { float a = TWOPI_64 * t; tc[t] = cosf(a); ts[t] = sinf(a); }
    __syncthreads();
    #pragma unroll
    for (int rep = 0; rep < 2; ++rep) {
        int oi = rep * 256 + t;
        int ky = oi >> 5, i = oi & 31;
        float re = 0.f, im = 0.f;
        #pragma unroll 8
        for (int h = 0; h < 64; ++h) {
            int gidx = (b * 64 + h) * 512 + ky * 32 + i;
            float gr = Gre[gidx], gi = Gim[gidx];
            int m = (kx * h) & 63;
            float c = tc[m], sv = ts[m];
            re += gr * c + gi * sv;   // * e^{-i theta}
            im += gi * c - gr * sv;
        }
        sXr[ky * 33 + i] = re;
        sXi[ky * 33 + i] = im;
    }
    __syncthreads();
    #pragma unroll
    for (int rep = 0; rep < 2; ++rep) {
        int oi = rep * 256 + t;
        int ky = oi & 15, o = oi >> 4;
        float re = 0.f, im = 0.f;
        #pragma unroll 8
        for (int i = 0; i < 32; ++i) {
            float xr = sXr[ky * 33 + i], xi = sXi[ky * 33 + i];
            int widx = (i * 32 + o) * 256 + x * 16 + ky;
            float wr = wre[widx], wi = wim[widx];
            re += xr * wr - xi * wi;
            im += xr * wi + xi * wr;
        }
        Yr[bid * 512 + ky * 32 + o] = re;
        Yi[bid * 512 + ky * 32 + o] = im;
    }
}

// ---------------- fused: iDFT over h + irfft over w + IN + MLP (x1) + MLP + IN (x2) -> osum ----------------
__global__ __launch_bounds__(256) void k_zx12(const float* __restrict__ Yr, const float* __restrict__ Yi,
                                              const float* __restrict__ mw1, const float* __restrict__ mb1,
                                              const float* __restrict__ mw2, const float* __restrict__ mb2,
                                              const float* __restrict__ ww1, const float* __restrict__ wb1,
                                              const float* __restrict__ ww2, const float* __restrict__ wb2,
                                              const float* __restrict__ xn,
                                              float* __restrict__ osum) {
    int bh = blockIdx.x;
    int b = bh >> 6, h = bh & 63;
    int t = threadIdx.x;
    __shared__ float tc[64], ts[64];
    __shared__ float red[8];
    __shared__ float sZr[16 * 33], sZi[16 * 33];
    __shared__ float sP[64 * 33];
    __shared__ float sH[64 * 65];
    __shared__ float sW1[2048], sW2[2048];
    __shared__ float sX[64 * 33];
    if (t < 64) { float a = TWOPI_64 * t; tc[t] = cosf(a); ts[t] = sinf(a); }
    for (int f = t; f < 2048; f += 256) { sW1[f] = mw1[f]; sW2[f] = mw2[f]; }
    // --- Z stage: Z[ky,o] = sum_kxi e^{+i kx h} Y[b,kxi,ky,o] ---
    #pragma unroll
    for (int rep = 0; rep < 2; ++rep) {
        int oi = rep * 256 + t;
        int ky = oi >> 5, o = oi & 31;
        float re = 0.f, im = 0.f;
        #pragma unroll 8
        for (int kxi = 0; kxi < 32; ++kxi) {
            int kx = kxi + (kxi < 16 ? 0 : 32);
            int m = (kx * h) & 63;
            float c = tc[m], sv = ts[m];
            int yidx = (b * 32 + kxi) * 512 + ky * 32 + o;
            float yr = Yr[yidx], yi = Yi[yidx];
            re += yr * c - yi * sv;
            im += yr * sv + yi * c;
        }
        sZr[(oi >> 5) * 33 + (oi & 31)] = re;
        sZi[(oi >> 5) * 33 + (oi & 31)] = im;
    }
    __syncthreads();
    // --- irfft over w + InstanceNorm -> sP ---
    float s = 0.f, s2 = 0.f;
    float vals[8];
    #pragma unroll
    for (int rep = 0; rep < 8; ++rep) {
        int idx = rep * 256 + t;
        int w = idx >> 5, o = idx & 31;
        float acc = sZr[o];  // ky=0: real part only
        #pragma unroll
        for (int ky = 1; ky < 16; ++ky) {
            int m = (ky * w) & 63;
            acc += 2.0f * (sZr[ky * 33 + o] * tc[m] - sZi[ky * 33 + o] * ts[m]);
        }
        acc *= (1.0f / 4096.0f);
        vals[rep] = acc;
        s += acc; s2 += acc * acc;
    }
    block_reduce2(s, s2, red);
    float mean = s * (1.0f / 2048.0f);
    float sc = rsqrtf(s2 * (1.0f / 2048.0f) - mean * mean + 1e-5f);
    #pragma unroll
    for (int rep = 0; rep < 8; ++rep) {
        int idx = rep * 256 + t;
        sP[(idx >> 5) * 33 + (idx & 31)] = (vals[rep] - mean) * sc;
    }
    __syncthreads();
    // --- x1 MLP hidden ---
    #pragma unroll
    for (int rep = 0; rep < 16; ++rep) {
        int idx = rep * 256 + t;
        int w = idx >> 6, k = idx & 63;
        float acc = mb1[k];
        #pragma unroll
        for (int c = 0; c < 32; ++c) acc += sP[w * 33 + c] * sW1[c * 64 + k];
        sH[w * 65 + k] = gelu_f(acc);
    }
    __syncthreads();
    // --- x1 MLP out -> vals1 (regs) ---
    float vals1[8];
    #pragma unroll
    for (int rep = 0; rep < 8; ++rep) {
        int idx = rep * 256 + t;
        int w = idx >> 5, o = idx & 31;
        float acc = mb2[o];
        #pragma unroll
        for (int k = 0; k < 64; ++k) acc += sH[w * 65 + k] * sW2[k * 32 + o];
        vals1[rep] = acc;
    }
    __syncthreads();
    // --- swap in x2 weights + xn row ---
    for (int f = t; f < 2048; f += 256) {
        sW1[f] = ww1[f]; sW2[f] = ww2[f];
        sX[(f >> 5) * 33 + (f & 31)] = xn[bh * 2048 + f];
    }
    __syncthreads();
    // --- x2 MLP hidden ---
    #pragma unroll
    for (int rep = 0; rep < 16; ++rep) {
        int idx = rep * 256 + t;
        int w = idx >> 6, k = idx & 63;
        float acc = wb1[k];
        #pragma unroll
        for (int c = 0; c < 32; ++c) acc += sX[w * 33 + c] * sW1[c * 64 + k];
        sH[w * 65 + k] = gelu_f(acc);
    }
    __syncthreads();
    // --- x2 MLP out + IN -> osum = x1 + x2 ---
    s = 0.f; s2 = 0.f;
    float vals2[8];
    #pragma unroll
    for (int rep = 0; rep < 8; ++rep) {
        int idx = rep * 256 + t;
        int w = idx >> 5, o = idx & 31;
        float acc = wb2[o];
        #pragma unroll
        for (int k = 0; k < 64; ++k) acc += sH[w * 65 + k] * sW2[k * 32 + o];
        vals2[rep] = acc;
        s += acc; s2 += acc * acc;
    }
    block_reduce2(s, s2, red);
    mean = s * (1.0f / 2048.0f);
    sc = rsqrtf(s2 * (1.0f / 2048.0f) - mean * mean + 1e-5f);
    #pragma unroll
    for (int rep = 0; rep < 8; ++rep) {
        int idx = rep * 256 + t;
        osum[bh * 2048 + idx] = vals1[rep] + (vals2[rep] - mean) * sc;
    }
}

// ---------------- GNO: 64 edges/block; wave = 32 edges x 16-o half; hi/lo f16 MFMA ----------------
// b2 folded into accumulator init: acc[r] starts at b2[i*32+o] so msg includes x@b2 (== old xb2)
__global__ __launch_bounds__(256, 4) void k_gno(const float* __restrict__ ea,
                                                const float* __restrict__ kw1, const float* __restrict__ kb1,
                                                const float* __restrict__ kb2,
                                                const _Float16* __restrict__ whi, const _Float16* __restrict__ wlo,
                                                const float* __restrict__ xn,
                                                const int* __restrict__ ei,
                                                float* __restrict__ agg) {
    // phase A: h[64][68] f32 (17408 B); phase B: sxT f16 [4][32*72+8] (18496 B) - shared buffer
    __shared__ __align__(16) float sbufF[4624];
    __shared__ float sB2[1024];
    __shared__ int ssrc[64], sdst[64];
    _Float16* sxTh = (_Float16*)sbufF;
    int t = threadIdx.x;
    int lane = t & 63, wv = t >> 6, quad = lane >> 4, l15 = lane & 15;
    int eg = wv >> 1;      // 32-edge group within the block's 64 edges
    int t2 = wv & 1;       // o-half: o = t2*16 + l15
    int e0 = blockIdx.x * 64;

    if (t < 64) ssrc[t] = ei[e0 + t];
    else if (t < 128) sdst[t - 64] = ei[E_ + e0 + t - 64];
    for (int f = t; f < 1024; f += 256) sB2[f] = kb2[f];
    // ---- phase 1: h = gelu(edge_attr @ kw1 + kb1) (f32, stride 68) ----
    {
        int r = t >> 2, k0 = (t & 3) * 16;
        const float* ep = ea + (e0 + r) * 6;
        float e6[6];
        #pragma unroll
        for (int d = 0; d < 6; ++d) e6[d] = ep[d];
        #pragma unroll
        for (int kk = 0; kk < 16; ++kk) {
            int k = k0 + kk;
            float acc = kb1[k];
            #pragma unroll
            for (int d = 0; d < 6; ++d) acc += e6[d] * kw1[d * 64 + k];
            sbufF[r * 68 + k] = gelu_f(acc);
        }
    }
    __syncthreads();

    // ---- phase 2: build A fragments (hi/lo) for this wave's 32 edges ----
    half8 ahi[2][2], alo[2][2];
    #pragma unroll
    for (int et = 0; et < 2; ++et) {
        #pragma unroll
        for (int kh = 0; kh < 2; ++kh) {
            const float* hp = sbufF + (eg * 32 + et * 16 + l15) * 68 + kh * 32 + quad * 8;
            float4 h0 = *(const float4*)hp;
            float4 h1 = *(const float4*)(hp + 4);
            float hv[8] = {h0.x, h0.y, h0.z, h0.w, h1.x, h1.y, h1.z, h1.w};
            half8 hh, hl;
            #pragma unroll
            for (int j = 0; j < 8; ++j) {
                _Float16 hi = (_Float16)hv[j];
                hh[j] = hi;
                hl[j] = (_Float16)(hv[j] - (float)hi);
            }
            ahi[et][kh] = hh;
            alo[et][kh] = hl;
        }
    }
    __syncthreads();

    // ---- phase 3: gather x rows, f16, fragment-permuted: sxTh[b*2312 + i*72 + perm(e)] ----
    {
        int b = t & 3, r = t >> 2;   // r = edge 0..63
        int s = ssrc[r];
        int pe = (r >> 5) * 32 + ((r >> 2) & 3) * 8 + ((r >> 4) & 1) * 4 + (r & 3);
        const float4* xp = (const float4*)(xn + (b * 4096 + s) * 32);
        _Float16* dp = sxTh + b * 2312 + pe;
        #pragma unroll
        for (int q = 0; q < 8; ++q) {
            float4 v = xp[q];
            dp[(q * 4 + 0) * 72] = (_Float16)v.x;
            dp[(q * 4 + 1) * 72] = (_Float16)v.y;
            dp[(q * 4 + 2) * 72] = (_Float16)v.z;
            dp[(q * 4 + 3) * 72] = (_Float16)v.w;
        }
    }
    __syncthreads();

    // ---- main loop over i ----
    float msg[4][2][4];  // [b][et][r], o = t2*16+l15
    #pragma unroll
    for (int b = 0; b < 4; ++b)
        #pragma unroll
        for (int et = 0; et < 2; ++et)
            #pragma unroll
            for (int r = 0; r < 4; ++r) msg[b][et][r] = 0.f;

    for (int i = 0; i < 32; ++i) {
        float b2v = sB2[i * 32 + t2 * 16 + l15];
        int f0 = (i * 4 + t2 * 2) * 512 + lane * 8;
        half8 bhi0 = *(const half8*)(whi + f0);
        half8 bhi1 = *(const half8*)(whi + f0 + 512);
        half8 blo0 = *(const half8*)(wlo + f0);
        half8 blo1 = *(const half8*)(wlo + f0 + 512);
        f32x4 acc[2];
        #pragma unroll
        for (int et = 0; et < 2; ++et) {
            f32x4 a = {b2v, b2v, b2v, b2v};
            a = __builtin_amdgcn_mfma_f32_16x16x32_f16(ahi[et][0], bhi0, a, 0, 0, 0);
            a = __builtin_amdgcn_mfma_f32_16x16x32_f16(ahi[et][1], bhi1, a, 0, 0, 0);
            a = __builtin_amdgcn_mfma_f32_16x16x32_f16(ahi[et][0], blo0, a, 0, 0, 0);
            a = __builtin_amdgcn_mfma_f32_16x16x32_f16(ahi[et][1], blo1, a, 0, 0, 0);
            a = __builtin_amdgcn_mfma_f32_16x16x32_f16(alo[et][0], bhi0, a, 0, 0, 0);
            a = __builtin_amdgcn_mfma_f32_16x16x32_f16(alo[et][1], bhi1, a, 0, 0, 0);
            acc[et] = a;
        }
        #pragma unroll
        for (int b = 0; b < 4; ++b) {
            const half8 xv = *(const half8*)(sxTh + b * 2312 + i * 72 + eg * 32 + quad * 8);
            #pragma unroll
            for (int et = 0; et < 2; ++et) {
                msg[b][et][0] += (float)xv[et * 4 + 0] * acc[et][0];
                msg[b][et][1] += (float)xv[et * 4 + 1] * acc[et][1];
                msg[b][et][2] += (float)xv[et * 4 + 2] * acc[et][2];
                msg[b][et][3] += (float)xv[et * 4 + 3] * acc[et][3];
            }
        }
    }

    // ---- scatter: agg[b, dst, o] += msg ----
    int o = t2 * 16 + l15;
    #pragma unroll
    for (int et = 0; et < 2; ++et) {
        #pragma unroll
        for (int r = 0; r < 4; ++r) {
            int row = eg * 32 + et * 16 + quad * 4 + r;
            int d = sdst[row];
            #pragma unroll
            for (int b = 0; b < 4; ++b) {
                atomicAdd(&agg[(b * 4096 + d) * 32 + o], msg[b][et][r]);
            }
        }
    }
}

// ---------------- final: out = gelu(osum + agg + xn@root + gbias) ----------------
__global__ __launch_bounds__(256) void k_final(const float* __restrict__ osum, const float* __restrict__ agg,
                                               const float* __restrict__ xn, const float* __restrict__ root,
                                               const float* __restrict__ gbias, float* __restrict__ out) {
    int bh = blockIdx.x;
    int t = threadIdx.x;
    __shared__ float sX[64 * 33];
    __shared__ float sR[1024];
    for (int f = t; f < 2048; f += 256) sX[(f >> 5) * 33 + (f & 31)] = xn[bh * 2048 + f];
    for (int f = t; f < 1024; f += 256) sR[f] = root[f];
    __syncthreads();
    #pragma unroll
    for (int rep = 0; rep < 8; ++rep) {
        int idx = rep * 256 + t;
        int w = idx >> 5, o = idx & 31;
        float acc = gbias[o] + osum[bh * 2048 + idx] + agg[bh * 2048 + idx];
        #pragma unroll
        for (int c = 0; c < 32; ++c) acc += sX[w * 33 + c] * sR[c * 32 + o];
        out[bh * 2048 + idx] = gelu_f(acc);
    }
}

extern "C" void kernel_launch(void* const* d_in, const int* in_sizes, int n_in,
                              void* d_out, int out_size, void* d_ws, size_t ws_size,
                              hipStream_t stream) {
    (void)in_sizes; (void)n_in; (void)out_size; (void)ws_size;
    const float* nodes  = (const float*)d_in[0];
    const int*   eidx   = (const int*)d_in[1];
    const float* eattr  = (const float*)d_in[2];
    const float* w1re   = (const float*)d_in[3];
    const float* w1im   = (const float*)d_in[4];
    const float* w2re   = (const float*)d_in[5];
    const float* w2im   = (const float*)d_in[6];
    const float* mlp_w1 = (const float*)d_in[7];
    const float* mlp_b1 = (const float*)d_in[8];
    const float* mlp_w2 = (const float*)d_in[9];
    const float* mlp_b2 = (const float*)d_in[10];
    const float* wm_w1  = (const float*)d_in[11];
    const float* wm_b1  = (const float*)d_in[12];
    const float* wm_w2  = (const float*)d_in[13];
    const float* wm_b2  = (const float*)d_in[14];
    const float* ker_w1 = (const float*)d_in[15];
    const float* ker_b1 = (const float*)d_in[16];
    const float* ker_w2 = (const float*)d_in[17];
    const float* ker_b2 = (const float*)d_in[18];
    const float* root   = (const float*)d_in[19];
    const float* gbias  = (const float*)d_in[20];
    float* out = (float*)d_out;

    char* ws = (char*)d_ws;
    size_t off = 0;
    auto alloc = [&](size_t bytes) {
        void* p = ws + off;
        off += (bytes + 255) & ~(size_t)255;
        return p;
    };
    float* xn   = (float*)alloc(524288 * 4);
    float* agg  = (float*)alloc(524288 * 4);
    float* osum = (float*)alloc(524288 * 4);
    float* Gre  = (float*)alloc(131072 * 4);
    float* Gim  = (float*)alloc(131072 * 4);
    float* Yr   = (float*)alloc(65536 * 4);
    float* Yi   = (float*)alloc(65536 * 4);
    _Float16* whi = (_Float16*)alloc(65536 * 2);
    _Float16* wlo = (_Float16*)alloc(65536 * 2);

    k_pre<<<384, 256, 0, stream>>>(nodes, ker_w2, xn, agg, Gre, Gim, whi, wlo);
    k_fxy<<<128, 256, 0, stream>>>(Gre, Gim, w1re, w1im, w2re, w2im, Yr, Yi);
    k_zx12<<<256, 256, 0, stream>>>(Yr, Yi, mlp_w1, mlp_b1, mlp_w2, mlp_b2,
                                    wm_w1, wm_b1, wm_w2, wm_b2, xn, osum);
    k_gno<<<2048, 256, 0, stream>>>(eattr, ker_w1, ker_b1, ker_b2, whi, wlo, xn, eidx, agg);
    k_final<<<256, 256, 0, stream>>>(osum, agg, xn, root, gbias, out);
}

// Round 4
// 275.598 us; speedup vs baseline: 1.2011x; 1.1554x over previous
//
#include <hip/hip_runtime.h>

#define B_ 4
#define H_ 64
#define W_ 64
#define C_ 32
#define N_ 4096
#define E_ 131072

typedef _Float16 half8 __attribute__((ext_vector_type(8)));
typedef float f32x4 __attribute__((ext_vector_type(4)));

__device__ __forceinline__ float gelu_f(float x) {
    return 0.5f * x * (1.0f + erff(x * 0.70710678118654752f));
}

#define TWOPI_64 (6.2831853071795864769f / 64.0f)

__device__ __forceinline__ void block_reduce2(float& s, float& s2, float* red) {
    #pragma unroll
    for (int off = 32; off > 0; off >>= 1) {
        s  += __shfl_down(s, off, 64);
        s2 += __shfl_down(s2, off, 64);
    }
    int lane = threadIdx.x & 63, wv = threadIdx.x >> 6;
    __syncthreads();
    if (lane == 0) { red[wv] = s; red[wv + 4] = s2; }
    __syncthreads();
    s  = red[0] + red[1] + red[2] + red[3];
    s2 = red[4] + red[5] + red[6] + red[7];
}

// ---------------- fused: InstanceNorm + DFT stage1 + agg-zero | w2 repack ----------------
__global__ __launch_bounds__(256) void k_pre(const float* __restrict__ nodes,
                                             const float* __restrict__ w2,
                                             float* __restrict__ xn,
                                             float* __restrict__ agg,
                                             float* __restrict__ Gre, float* __restrict__ Gim,
                                             _Float16* __restrict__ whi, _Float16* __restrict__ wlo) {
    int t = threadIdx.x;
    if (blockIdx.x >= 256) {
        int g0 = (blockIdx.x - 256) * 512 + t;
        #pragma unroll
        for (int rep = 0; rep < 2; ++rep) {
            int g = g0 + rep * 256;
            int j = g & 7, l = (g >> 3) & 63, fid = g >> 9;
            int i = fid >> 2, t2 = (fid >> 1) & 1, kh = fid & 1;
            int quad = l >> 4, l15 = l & 15;
            int k = kh * 32 + quad * 8 + j;
            int n = i * 32 + t2 * 16 + l15;
            float v = w2[k * 1024 + n];
            _Float16 hi = (_Float16)v;
            whi[g] = hi;
            wlo[g] = (_Float16)(v - (float)hi);
        }
        return;
    }
    int bh = blockIdx.x;
    __shared__ float sx[2048];
    __shared__ float tc[64], ts[64];
    __shared__ float red[8];
    const float4* src = (const float4*)(nodes + bh * 2048);
    float4* dst = (float4*)(xn + bh * 2048);
    float4* az = (float4*)(agg + bh * 2048);
    if (t < 64) { float a = TWOPI_64 * t; tc[t] = cosf(a); ts[t] = sinf(a); }
    float4 v0 = src[t * 2], v1 = src[t * 2 + 1];
    float s  = v0.x + v0.y + v0.z + v0.w + v1.x + v1.y + v1.z + v1.w;
    float s2 = v0.x*v0.x + v0.y*v0.y + v0.z*v0.z + v0.w*v0.w
             + v1.x*v1.x + v1.y*v1.y + v1.z*v1.z + v1.w*v1.w;
    block_reduce2(s, s2, red);
    float mean = s * (1.0f / 2048.0f);
    float var  = s2 * (1.0f / 2048.0f) - mean * mean;
    float sc = rsqrtf(var + 1e-5f);
    v0.x = (v0.x - mean) * sc; v0.y = (v0.y - mean) * sc;
    v0.z = (v0.z - mean) * sc; v0.w = (v0.w - mean) * sc;
    v1.x = (v1.x - mean) * sc; v1.y = (v1.y - mean) * sc;
    v1.z = (v1.z - mean) * sc; v1.w = (v1.w - mean) * sc;
    dst[t * 2] = v0; dst[t * 2 + 1] = v1;
    float4 z = {0.f, 0.f, 0.f, 0.f};
    az[t * 2] = z; az[t * 2 + 1] = z;
    ((float4*)sx)[t * 2] = v0;
    ((float4*)sx)[t * 2 + 1] = v1;
    __syncthreads();
    for (int rep = 0; rep < 2; ++rep) {
        int oi = rep * 256 + t;
        int ky = oi >> 5, i = oi & 31;
        float re = 0.f, im = 0.f;
        #pragma unroll 8
        for (int w = 0; w < 64; ++w) {
            float v = sx[w * 32 + i];
            int m = (ky * w) & 63;
            re += v * tc[m];
            im -= v * ts[m];
        }
        Gre[bh * 512 + oi] = re;
        Gim[bh * 512 + oi] = im;
    }
}

// ---------------- fused: DFT stage2 (over h) + spectral multiply -> Yf ----------------
__global__ __launch_bounds__(256) void k_fxy(const float* __restrict__ Gre, const float* __restrict__ Gim,
                                             const float* __restrict__ w1re, const float* __restrict__ w1im,
                                             const float* __restrict__ w2re, const float* __restrict__ w2im,
                                             float* __restrict__ Yr, float* __restrict__ Yi) {
    int bid = blockIdx.x;  // 0..127 = (b, kxi)
    int b = bid >> 5, kxi = bid & 31;
    int kx = kxi + (kxi < 16 ? 0 : 32);
    int x = kxi & 15;
    const float* wre = (kxi < 16) ? w1re : w2re;
    const float* wim = (kxi < 16) ? w1im : w2im;
    int t = threadIdx.x;
    __shared__ float tc[64], ts[64];
    __shared__ float sXr[16 * 33], sXi[16 * 33];
    if (t < 64) { float a = TWOPI_64 * t; tc[t] = cosf(a); ts[t] = sinf(a); }
    __syncthreads();
    for (int rep = 0; rep < 2; ++rep) {
        int oi = rep * 256 + t;
        int ky = oi >> 5, i = oi & 31;
        float re = 0.f, im = 0.f;
        #pragma unroll 8
        for (int h = 0; h < 64; ++h) {
            int gidx = (b * 64 + h) * 512 + ky * 32 + i;
            float gr = Gre[gidx], gi = Gim[gidx];
            int m = (kx * h) & 63;
            float c = tc[m], sv = ts[m];
            re += gr * c + gi * sv;   // * e^{-i theta}
            im += gi * c - gr * sv;
        }
        sXr[ky * 33 + i] = re;
        sXi[ky * 33 + i] = im;
    }
    __syncthreads();
    for (int rep = 0; rep < 2; ++rep) {
        int oi = rep * 256 + t;
        int ky = oi & 15, o = oi >> 4;
        float re = 0.f, im = 0.f;
        #pragma unroll 4
        for (int i = 0; i < 32; ++i) {
            float xr = sXr[ky * 33 + i], xi = sXi[ky * 33 + i];
            int widx = (i * 32 + o) * 256 + x * 16 + ky;
            float wr = wre[widx], wi = wim[widx];
            re += xr * wr - xi * wi;
            im += xr * wi + xi * wr;
        }
        Yr[bid * 512 + ky * 32 + o] = re;
        Yi[bid * 512 + ky * 32 + o] = im;
    }
}

// ---------------- iDFT over h + irfft over w + IN + MLP -> osum = x1 (register-lean) ----------------
__global__ __launch_bounds__(256) void k_zx1(const float* __restrict__ Yr, const float* __restrict__ Yi,
                                             const float* __restrict__ mw1, const float* __restrict__ mb1,
                                             const float* __restrict__ mw2, const float* __restrict__ mb2,
                                             float* __restrict__ osum) {
    int bh = blockIdx.x;
    int b = bh >> 6, h = bh & 63;
    int t = threadIdx.x;
    __shared__ float tc[64], ts[64];
    __shared__ float red[8];
    __shared__ float sZr[16 * 33], sZi[16 * 33];
    __shared__ float sP[64 * 33];
    __shared__ float sH[64 * 65];
    __shared__ float sW1[2048], sW2[2048];
    if (t < 64) { float a = TWOPI_64 * t; tc[t] = cosf(a); ts[t] = sinf(a); }
    for (int f = t; f < 2048; f += 256) { sW1[f] = mw1[f]; sW2[f] = mw2[f]; }
    // --- Z stage ---
    for (int rep = 0; rep < 2; ++rep) {
        int oi = rep * 256 + t;
        int ky = oi >> 5, o = oi & 31;
        float re = 0.f, im = 0.f;
        #pragma unroll 4
        for (int kxi = 0; kxi < 32; ++kxi) {
            int kx = kxi + (kxi < 16 ? 0 : 32);
            int m = (kx * h) & 63;
            float c = tc[m], sv = ts[m];
            int yidx = (b * 32 + kxi) * 512 + ky * 32 + o;
            float yr = Yr[yidx], yi = Yi[yidx];
            re += yr * c - yi * sv;
            im += yr * sv + yi * c;
        }
        sZr[ky * 33 + o] = re;
        sZi[ky * 33 + o] = im;
    }
    __syncthreads();
    // --- irfft over w + InstanceNorm -> sP ---
    float s = 0.f, s2 = 0.f;
    float vals[8];
    #pragma unroll
    for (int rep = 0; rep < 8; ++rep) {
        int idx = rep * 256 + t;
        int w = idx >> 5, o = idx & 31;
        float acc = sZr[o];  // ky=0: real part only (irfft drops imag of DC bin)
        #pragma unroll 5
        for (int ky = 1; ky < 16; ++ky) {
            int m = (ky * w) & 63;
            acc += 2.0f * (sZr[ky * 33 + o] * tc[m] - sZi[ky * 33 + o] * ts[m]);
        }
        acc *= (1.0f / 4096.0f);
        vals[rep] = acc;
        s += acc; s2 += acc * acc;
    }
    block_reduce2(s, s2, red);
    float mean = s * (1.0f / 2048.0f);
    float sc = rsqrtf(s2 * (1.0f / 2048.0f) - mean * mean + 1e-5f);
    #pragma unroll
    for (int rep = 0; rep < 8; ++rep) {
        int idx = rep * 256 + t;
        sP[(idx >> 5) * 33 + (idx & 31)] = (vals[rep] - mean) * sc;
    }
    __syncthreads();
    // --- MLP hidden ---
    for (int rep = 0; rep < 16; ++rep) {
        int idx = rep * 256 + t;
        int w = idx >> 6, k = idx & 63;
        float acc = mb1[k];
        #pragma unroll 4
        for (int c = 0; c < 32; ++c) acc += sP[w * 33 + c] * sW1[c * 64 + k];
        sH[w * 65 + k] = gelu_f(acc);
    }
    __syncthreads();
    // --- MLP out -> osum ---
    for (int rep = 0; rep < 8; ++rep) {
        int idx = rep * 256 + t;
        int w = idx >> 5, o = idx & 31;
        float acc = mb2[o];
        #pragma unroll 4
        for (int k = 0; k < 64; ++k) acc += sH[w * 65 + k] * sW2[k * 32 + o];
        osum[bh * 2048 + idx] = acc;
    }
}

// ---------------- x2 = InstanceNorm(MLP(xn)); osum += x2 (register-lean) ----------------
__global__ __launch_bounds__(256) void k_x2(const float* __restrict__ xn,
                                            const float* __restrict__ ww1, const float* __restrict__ wb1,
                                            const float* __restrict__ ww2, const float* __restrict__ wb2,
                                            float* __restrict__ osum) {
    int bh = blockIdx.x;
    int t = threadIdx.x;
    __shared__ float red[8];
    __shared__ float sX[64 * 33];
    __shared__ float sH[64 * 65];
    __shared__ float sW1[2048], sW2[2048];
    for (int f = t; f < 2048; f += 256) {
        sW1[f] = ww1[f]; sW2[f] = ww2[f];
        sX[(f >> 5) * 33 + (f & 31)] = xn[bh * 2048 + f];
    }
    __syncthreads();
    for (int rep = 0; rep < 16; ++rep) {
        int idx = rep * 256 + t;
        int w = idx >> 6, k = idx & 63;
        float acc = wb1[k];
        #pragma unroll 4
        for (int c = 0; c < 32; ++c) acc += sX[w * 33 + c] * sW1[c * 64 + k];
        sH[w * 65 + k] = gelu_f(acc);
    }
    __syncthreads();
    float s = 0.f, s2 = 0.f;
    float vals2[8];
    #pragma unroll
    for (int rep = 0; rep < 8; ++rep) {
        int idx = rep * 256 + t;
        int w = idx >> 5, o = idx & 31;
        float acc = wb2[o];
        #pragma unroll 4
        for (int k = 0; k < 64; ++k) acc += sH[w * 65 + k] * sW2[k * 32 + o];
        vals2[rep] = acc;
        s += acc; s2 += acc * acc;
    }
    block_reduce2(s, s2, red);
    float mean = s * (1.0f / 2048.0f);
    float sc = rsqrtf(s2 * (1.0f / 2048.0f) - mean * mean + 1e-5f);
    #pragma unroll
    for (int rep = 0; rep < 8; ++rep) {
        int idx = rep * 256 + t;
        osum[bh * 2048 + idx] += (vals2[rep] - mean) * sc;
    }
}

// ---------------- GNO: 64 edges/block; wave = 32 edges x 16-o half; hi/lo f16 MFMA ----------------
__global__ __launch_bounds__(256, 4) void k_gno(const float* __restrict__ ea,
                                                const float* __restrict__ kw1, const float* __restrict__ kb1,
                                                const float* __restrict__ kb2,
                                                const _Float16* __restrict__ whi, const _Float16* __restrict__ wlo,
                                                const float* __restrict__ xn,
                                                const int* __restrict__ ei,
                                                float* __restrict__ agg) {
    __shared__ __align__(16) float sbufF[4624];
    __shared__ float sB2[1024];
    __shared__ int ssrc[64], sdst[64];
    _Float16* sxTh = (_Float16*)sbufF;
    int t = threadIdx.x;
    int lane = t & 63, wv = t >> 6, quad = lane >> 4, l15 = lane & 15;
    int eg = wv >> 1;      // 32-edge group within the block's 64 edges
    int t2 = wv & 1;       // o-half: o = t2*16 + l15
    int e0 = blockIdx.x * 64;

    if (t < 64) ssrc[t] = ei[e0 + t];
    else if (t < 128) sdst[t - 64] = ei[E_ + e0 + t - 64];
    for (int f = t; f < 1024; f += 256) sB2[f] = kb2[f];
    // ---- phase 1: h = gelu(edge_attr @ kw1 + kb1) (f32, stride 68) ----
    {
        int r = t >> 2, k0 = (t & 3) * 16;
        const float* ep = ea + (e0 + r) * 6;
        float e6[6];
        #pragma unroll
        for (int d = 0; d < 6; ++d) e6[d] = ep[d];
        #pragma unroll
        for (int kk = 0; kk < 16; ++kk) {
            int k = k0 + kk;
            float acc = kb1[k];
            #pragma unroll
            for (int d = 0; d < 6; ++d) acc += e6[d] * kw1[d * 64 + k];
            sbufF[r * 68 + k] = gelu_f(acc);
        }
    }
    __syncthreads();

    // ---- phase 2: build A fragments (hi/lo) for this wave's 32 edges ----
    half8 ahi[2][2], alo[2][2];
    #pragma unroll
    for (int et = 0; et < 2; ++et) {
        #pragma unroll
        for (int kh = 0; kh < 2; ++kh) {
            const float* hp = sbufF + (eg * 32 + et * 16 + l15) * 68 + kh * 32 + quad * 8;
            float4 h0 = *(const float4*)hp;
            float4 h1 = *(const float4*)(hp + 4);
            float hv[8] = {h0.x, h0.y, h0.z, h0.w, h1.x, h1.y, h1.z, h1.w};
            half8 hh, hl;
            #pragma unroll
            for (int j = 0; j < 8; ++j) {
                _Float16 hi = (_Float16)hv[j];
                hh[j] = hi;
                hl[j] = (_Float16)(hv[j] - (float)hi);
            }
            ahi[et][kh] = hh;
            alo[et][kh] = hl;
        }
    }
    __syncthreads();

    // ---- phase 3: gather x rows, f16, fragment-permuted: sxTh[b*2312 + i*72 + perm(e)] ----
    {
        int b = t & 3, r = t >> 2;   // r = edge 0..63
        int s = ssrc[r];
        int pe = (r >> 5) * 32 + ((r >> 2) & 3) * 8 + ((r >> 4) & 1) * 4 + (r & 3);
        const float4* xp = (const float4*)(xn + (b * 4096 + s) * 32);
        _Float16* dp = sxTh + b * 2312 + pe;
        #pragma unroll
        for (int q = 0; q < 8; ++q) {
            float4 v = xp[q];
            dp[(q * 4 + 0) * 72] = (_Float16)v.x;
            dp[(q * 4 + 1) * 72] = (_Float16)v.y;
            dp[(q * 4 + 2) * 72] = (_Float16)v.z;
            dp[(q * 4 + 3) * 72] = (_Float16)v.w;
        }
    }
    __syncthreads();

    // ---- main loop over i ----
    float msg[4][2][4];  // [b][et][r], o = t2*16+l15
    #pragma unroll
    for (int b = 0; b < 4; ++b)
        #pragma unroll
        for (int et = 0; et < 2; ++et)
            #pragma unroll
            for (int r = 0; r < 4; ++r) msg[b][et][r] = 0.f;

    for (int i = 0; i < 32; ++i) {
        float b2v = sB2[i * 32 + t2 * 16 + l15];
        int f0 = (i * 4 + t2 * 2) * 512 + lane * 8;
        half8 bhi0 = *(const half8*)(whi + f0);
        half8 bhi1 = *(const half8*)(whi + f0 + 512);
        half8 blo0 = *(const half8*)(wlo + f0);
        half8 blo1 = *(const half8*)(wlo + f0 + 512);
        f32x4 acc[2];
        #pragma unroll
        for (int et = 0; et < 2; ++et) {
            f32x4 a = {b2v, b2v, b2v, b2v};
            a = __builtin_amdgcn_mfma_f32_16x16x32_f16(ahi[et][0], bhi0, a, 0, 0, 0);
            a = __builtin_amdgcn_mfma_f32_16x16x32_f16(ahi[et][1], bhi1, a, 0, 0, 0);
            a = __builtin_amdgcn_mfma_f32_16x16x32_f16(ahi[et][0], blo0, a, 0, 0, 0);
            a = __builtin_amdgcn_mfma_f32_16x16x32_f16(ahi[et][1], blo1, a, 0, 0, 0);
            a = __builtin_amdgcn_mfma_f32_16x16x32_f16(alo[et][0], bhi0, a, 0, 0, 0);
            a = __builtin_amdgcn_mfma_f32_16x16x32_f16(alo[et][1], bhi1, a, 0, 0, 0);
            acc[et] = a;
        }
        #pragma unroll
        for (int b = 0; b < 4; ++b) {
            const half8 xv = *(const half8*)(sxTh + b * 2312 + i * 72 + eg * 32 + quad * 8);
            #pragma unroll
            for (int et = 0; et < 2; ++et) {
                msg[b][et][0] += (float)xv[et * 4 + 0] * acc[et][0];
                msg[b][et][1] += (float)xv[et * 4 + 1] * acc[et][1];
                msg[b][et][2] += (float)xv[et * 4 + 2] * acc[et][2];
                msg[b][et][3] += (float)xv[et * 4 + 3] * acc[et][3];
            }
        }
    }

    // ---- scatter: agg[b, dst, o] += msg ----
    int o = t2 * 16 + l15;
    #pragma unroll
    for (int et = 0; et < 2; ++et) {
        #pragma unroll
        for (int r = 0; r < 4; ++r) {
            int row = eg * 32 + et * 16 + quad * 4 + r;
            int d = sdst[row];
            #pragma unroll
            for (int b = 0; b < 4; ++b) {
                atomicAdd(&agg[(b * 4096 + d) * 32 + o], msg[b][et][r]);
            }
        }
    }
}

// ---------------- final: out = gelu(osum + agg + xn@root + gbias) ----------------
__global__ __launch_bounds__(256) void k_final(const float* __restrict__ osum, const float* __restrict__ agg,
                                               const float* __restrict__ xn, const float* __restrict__ root,
                                               const float* __restrict__ gbias, float* __restrict__ out) {
    int bh = blockIdx.x;
    int t = threadIdx.x;
    __shared__ float sX[64 * 33];
    __shared__ float sR[1024];
    for (int f = t; f < 2048; f += 256) sX[(f >> 5) * 33 + (f & 31)] = xn[bh * 2048 + f];
    for (int f = t; f < 1024; f += 256) sR[f] = root[f];
    __syncthreads();
    for (int rep = 0; rep < 8; ++rep) {
        int idx = rep * 256 + t;
        int w = idx >> 5, o = idx & 31;
        float acc = gbias[o] + osum[bh * 2048 + idx] + agg[bh * 2048 + idx];
        #pragma unroll 4
        for (int c = 0; c < 32; ++c) acc += sX[w * 33 + c] * sR[c * 32 + o];
        out[bh * 2048 + idx] = gelu_f(acc);
    }
}

extern "C" void kernel_launch(void* const* d_in, const int* in_sizes, int n_in,
                              void* d_out, int out_size, void* d_ws, size_t ws_size,
                              hipStream_t stream) {
    (void)in_sizes; (void)n_in; (void)out_size; (void)ws_size;
    const float* nodes  = (const float*)d_in[0];
    const int*   eidx   = (const int*)d_in[1];
    const float* eattr  = (const float*)d_in[2];
    const float* w1re   = (const float*)d_in[3];
    const float* w1im   = (const float*)d_in[4];
    const float* w2re   = (const float*)d_in[5];
    const float* w2im   = (const float*)d_in[6];
    const float* mlp_w1 = (const float*)d_in[7];
    const float* mlp_b1 = (const float*)d_in[8];
    const float* mlp_w2 = (const float*)d_in[9];
    const float* mlp_b2 = (const float*)d_in[10];
    const float* wm_w1  = (const float*)d_in[11];
    const float* wm_b1  = (const float*)d_in[12];
    const float* wm_w2  = (const float*)d_in[13];
    const float* wm_b2  = (const float*)d_in[14];
    const float* ker_w1 = (const float*)d_in[15];
    const float* ker_b1 = (const float*)d_in[16];
    const float* ker_w2 = (const float*)d_in[17];
    const float* ker_b2 = (const float*)d_in[18];
    const float* root   = (const float*)d_in[19];
    const float* gbias  = (const float*)d_in[20];
    float* out = (float*)d_out;

    char* ws = (char*)d_ws;
    size_t off = 0;
    auto alloc = [&](size_t bytes) {
        void* p = ws + off;
        off += (bytes + 255) & ~(size_t)255;
        return p;
    };
    float* xn   = (float*)alloc(524288 * 4);
    float* agg  = (float*)alloc(524288 * 4);
    float* osum = (float*)alloc(524288 * 4);
    float* Gre  = (float*)alloc(131072 * 4);
    float* Gim  = (float*)alloc(131072 * 4);
    float* Yr   = (float*)alloc(65536 * 4);
    float* Yi   = (float*)alloc(65536 * 4);
    _Float16* whi = (_Float16*)alloc(65536 * 2);
    _Float16* wlo = (_Float16*)alloc(65536 * 2);

    k_pre<<<384, 256, 0, stream>>>(nodes, ker_w2, xn, agg, Gre, Gim, whi, wlo);
    k_fxy<<<128, 256, 0, stream>>>(Gre, Gim, w1re, w1im, w2re, w2im, Yr, Yi);
    k_zx1<<<256, 256, 0, stream>>>(Yr, Yi, mlp_w1, mlp_b1, mlp_w2, mlp_b2, osum);
    k_x2<<<256, 256, 0, stream>>>(xn, wm_w1, wm_b1, wm_w2, wm_b2, osum);
    k_gno<<<2048, 256, 0, stream>>>(eattr, ker_w1, ker_b1, ker_b2, whi, wlo, xn, eidx, agg);
    k_final<<<256, 256, 0, stream>>>(osum, agg, xn, root, gbias, out);
}